// Round 5
// baseline (475.479 us; speedup 1.0000x reference)
//
#include <hip/hip_runtime.h>
#include <hip/hip_cooperative_groups.h>

namespace cg = cooperative_groups;

#define NG    64
#define NPG   128
#define KNN   100
#define FIN   6
#define WID   128
#define D2    768
#define NEG   0.01f
#define INV101 (1.0f/101.0f)
#define BNEPS 1e-5f
#define BIG   1e30f

__device__ __forceinline__ float leaky(float v) { return v > 0.f ? v : NEG * v; }

// monotone float -> uint mapping (a<b as float  <=>  ford(a)<ford(b) as uint)
__device__ __forceinline__ unsigned ford(float f) {
    unsigned u = __float_as_uint(f);
    return (u >> 31) ? ~u : (u | 0x80000000u);
}

// One cooperative kernel: grid 256 blocks x 256 threads, 1 block/CU.
// Block b: graph g = b&63, row-slab i0 = (b>>6)*32. (g=b&63 keeps a graph's
// 4 slabs on one XCD: b%8 == (b+64)%8.)
__global__ __launch_bounds__(256, 1) void k_mega(
    const float* __restrict__ x,
    const float* __restrict__ W1, const float* __restrict__ b1,
    const float* __restrict__ Wc, const float* __restrict__ bc,
    const float* __restrict__ bng, const float* __restrict__ bnb,
    const float* __restrict__ linW, const float* __restrict__ linb,
    const float* __restrict__ outW, const float* __restrict__ outb,
    float* __restrict__ A, float* __restrict__ H1, float* __restrict__ H2,
    float* __restrict__ Zp, float* __restrict__ Zp3,
    float* __restrict__ ZT0, float* __restrict__ ZT1, float* __restrict__ out)
{
    cg::grid_group grid = cg::this_grid();
    const int b    = blockIdx.x;
    const int g    = b & 63;
    const int slab = b >> 6;
    const int i0   = slab * 32;
    const int t    = threadIdx.x;

    __shared__ float xg[NPG * FIN];      // 3 KB   (persists ph0 -> ph1)
    __shared__ float sq[NPG];            // 0.5 KB
    __shared__ float A2s[32 * 132];      // 16.9 KB (persists ph1 -> convs)
    __shared__ float Ps[32 * 132];       // 16.9 KB (P slab / W panel / outW)
    __shared__ float Bs[NPG * NPG];      // 64 KB  (D slab / A full / h full)
    __shared__ float p2[32 * FIN];
    __shared__ float W1s[FIN * WID];
    __shared__ float b1s[WID];
    __shared__ float red[4 * 4 * 64];    // 4 KB   (tail reduce)

    // ================= Phase 0: kNN -> A = (I+M)/101 =================
    {
        const float* xp = x + g * NPG * FIN;
        for (int e = t; e < NPG * FIN; e += 256) xg[e] = xp[e];
        __syncthreads();
        if (t < NPG) {
            float s = 0.f;
            #pragma unroll
            for (int c = 0; c < FIN; ++c) { float v = xg[t * FIN + c]; s = fmaf(v, v, s); }
            sq[t] = s;
        }
        __syncthreads();
        for (int e = t; e < 32 * NPG; e += 256) {
            int il = e >> 7, j = e & 127;
            int i = i0 + il;
            float d;
            if (j == i) d = BIG;
            else {
                float dot = 0.f;
                #pragma unroll
                for (int c = 0; c < FIN; ++c) dot = fmaf(xg[i * FIN + c], xg[j * FIN + c], dot);
                d = sq[i] + sq[j] - 2.f * dot;
            }
            Bs[il * 128 + j] = d;
        }
        __syncthreads();
        // rank-select: thread -> (row il, 16 cols j0..j0+15), lex keys in regs
        int il = t >> 3, j0 = (t & 7) * 16;
        const float* Drow = &Bs[il * 128];
        unsigned long long jk[16];
        int cnt[16];
        #pragma unroll
        for (int u = 0; u < 16; ++u) {
            jk[u] = ((unsigned long long)ford(Drow[j0 + u]) << 32) | (unsigned)(j0 + u);
            cnt[u] = 0;
        }
        for (int k = 0; k < 128; ++k) {
            unsigned long long kk = ((unsigned long long)ford(Drow[k]) << 32) | (unsigned)k;
            #pragma unroll
            for (int u = 0; u < 16; ++u) cnt[u] += (kk < jk[u]) ? 1 : 0;
        }
        int i = i0 + il;
        float av[16];
        #pragma unroll
        for (int u = 0; u < 16; ++u)
            av[u] = (cnt[u] < KNN || (j0 + u) == i) ? INV101 : 0.f;
        float* Ag = A + (size_t)g * NPG * NPG + (size_t)i * NPG + j0;
        #pragma unroll
        for (int q = 0; q < 4; ++q)
            *(float4*)&Ag[q * 4] = make_float4(av[q*4], av[q*4+1], av[q*4+2], av[q*4+3]);
    }
    grid.sync();   // S1

    // ============ Phase 1: A2 slab = (A@A)[i0:i0+32,:] (kept in LDS) + conv1 ============
    {
        const float* Ag = A + (size_t)g * NPG * NPG;
        for (int t4 = t; t4 < NPG * NPG / 4; t4 += 256)
            *(float4*)&Bs[t4 * 4] = *(const float4*)&Ag[t4 * 4];
        for (int e = t; e < FIN * WID; e += 256) W1s[e] = W1[e];
        if (t < WID) b1s[t] = b1[t];
        __syncthreads();
        int ty = t >> 4, tx = t & 15;
        int r0 = ty * 2, cj = tx * 8;
        float acc[2][8] = {};
        for (int k = 0; k < NPG; ++k) {
            float a0 = Bs[(i0 + r0) * 128 + k];
            float a1 = Bs[(i0 + r0 + 1) * 128 + k];
            float4 q0 = *(const float4*)&Bs[k * 128 + cj];
            float4 q1 = *(const float4*)&Bs[k * 128 + cj + 4];
            float bb[8] = {q0.x, q0.y, q0.z, q0.w, q1.x, q1.y, q1.z, q1.w};
            #pragma unroll
            for (int c = 0; c < 8; ++c) {
                acc[0][c] = fmaf(a0, bb[c], acc[0][c]);
                acc[1][c] = fmaf(a1, bb[c], acc[1][c]);
            }
        }
        #pragma unroll
        for (int r = 0; r < 2; ++r) {
            *(float4*)&A2s[(r0 + r) * 132 + cj]     = make_float4(acc[r][0], acc[r][1], acc[r][2], acc[r][3]);
            *(float4*)&A2s[(r0 + r) * 132 + cj + 4] = make_float4(acc[r][4], acc[r][5], acc[r][6], acc[r][7]);
        }
        __syncthreads();
        // p2 = A2_slab @ x  (32 x 6)
        if (t < 32 * FIN) {
            int i = t / FIN, d = t - i * FIN;
            float s = 0.f;
            for (int k = 0; k < NPG; ++k) s = fmaf(A2s[i * 132 + k], xg[k * FIN + d], s);
            p2[t] = s;
        }
        __syncthreads();
        // h1 slab = leaky(p2 @ W1 + b1) -> H1
        for (int e = t; e < 32 * WID; e += 256) {
            int i = e >> 7, o = e & 127;
            float s = b1s[o];
            #pragma unroll
            for (int d = 0; d < FIN; ++d) s = fmaf(p2[i * FIN + d], W1s[d * WID + o], s);
            H1[(size_t)(g * NPG + i0 + i) * WID + o] = leaky(s);
        }
    }
    grid.sync();   // S2

    // ============ Phases 2-3: conv2 (h1->h2, pool h1), conv3 (h2->pool3 partials, pool h2) ============
    for (int f = 0; f < 2; ++f) {
        const float* Hin  = f ? H2 : H1;
        const float* W    = Wc + f * WID * WID;
        const float* bias = bc + f * WID;
        const float* hg = Hin + (size_t)g * NPG * WID;
        for (int t4 = t; t4 < NPG * WID / 4; t4 += 256)
            *(float4*)&Bs[t4 * 4] = *(const float4*)&hg[t4 * 4];
        __syncthreads();
        // full pool of the staged INPUT h -> Zp columns [f*256, f*256+256)
        if (slab == 0 && t < WID) {
            float sm = 0.f, mx = -BIG;
            for (int i = 0; i < NPG; ++i) { float v = Bs[i * WID + t]; sm += v; mx = fmaxf(mx, v); }
            Zp[g * D2 + f * 256 + t]       = sm * (1.f / NPG);
            Zp[g * D2 + f * 256 + WID + t] = mx;
        }
        int ty = t >> 4, tx = t & 15;
        int r0 = ty * 2, cj = tx * 8;
        float acc[2][8] = {};
        for (int k = 0; k < NPG; ++k) {
            float a0 = A2s[r0 * 132 + k];
            float a1 = A2s[(r0 + 1) * 132 + k];
            float4 q0 = *(const float4*)&Bs[k * WID + cj];
            float4 q1 = *(const float4*)&Bs[k * WID + cj + 4];
            float bb[8] = {q0.x, q0.y, q0.z, q0.w, q1.x, q1.y, q1.z, q1.w};
            #pragma unroll
            for (int c = 0; c < 8; ++c) {
                acc[0][c] = fmaf(a0, bb[c], acc[0][c]);
                acc[1][c] = fmaf(a1, bb[c], acc[1][c]);
            }
        }
        #pragma unroll
        for (int r = 0; r < 2; ++r) {
            *(float4*)&Ps[(r0 + r) * 132 + cj]     = make_float4(acc[r][0], acc[r][1], acc[r][2], acc[r][3]);
            *(float4*)&Ps[(r0 + r) * 132 + cj + 4] = make_float4(acc[r][4], acc[r][5], acc[r][6], acc[r][7]);
        }
        __syncthreads();
        float o2[2][8] = {};
        for (int d = 0; d < NPG; ++d) {
            float a0 = Ps[r0 * 132 + d];
            float a1 = Ps[(r0 + 1) * 132 + d];
            float4 w0 = *(const float4*)&W[d * WID + cj];
            float4 w1 = *(const float4*)&W[d * WID + cj + 4];
            float bb[8] = {w0.x, w0.y, w0.z, w0.w, w1.x, w1.y, w1.z, w1.w};
            #pragma unroll
            for (int c = 0; c < 8; ++c) {
                o2[0][c] = fmaf(a0, bb[c], o2[0][c]);
                o2[1][c] = fmaf(a1, bb[c], o2[1][c]);
            }
        }
        #pragma unroll
        for (int r = 0; r < 2; ++r)
            #pragma unroll
            for (int c = 0; c < 8; ++c)
                o2[r][c] = leaky(o2[r][c] + bias[cj + c]);
        if (f == 0) {
            #pragma unroll
            for (int r = 0; r < 2; ++r) {
                *(float4*)&H2[(size_t)(g * NPG + i0 + r0 + r) * WID + cj]     = make_float4(o2[r][0], o2[r][1], o2[r][2], o2[r][3]);
                *(float4*)&H2[(size_t)(g * NPG + i0 + r0 + r) * WID + cj + 4] = make_float4(o2[r][4], o2[r][5], o2[r][6], o2[r][7]);
            }
        } else {
            __syncthreads();   // all reads of Ps (P) done -> safe to overwrite with h3
            #pragma unroll
            for (int r = 0; r < 2; ++r) {
                *(float4*)&Ps[(r0 + r) * 132 + cj]     = make_float4(o2[r][0], o2[r][1], o2[r][2], o2[r][3]);
                *(float4*)&Ps[(r0 + r) * 132 + cj + 4] = make_float4(o2[r][4], o2[r][5], o2[r][6], o2[r][7]);
            }
            __syncthreads();
            // partial pool of this 32-row h3 slab -> Zp3[(g*4+slab)][{sum,max}][128]
            if (t < WID) {
                float sm = 0.f, mx = -BIG;
                for (int i = 0; i < 32; ++i) { float v = Ps[i * 132 + t]; sm += v; mx = fmaxf(mx, v); }
                Zp3[(size_t)(g * 4 + slab) * 256 + t]       = sm;
                Zp3[(size_t)(g * 4 + slab) * 256 + 128 + t] = mx;
            }
        }
        grid.sync();   // S3, S4
    }

    // ============ Phase 4: BN (batch stats) + transpose -> ZT0[768][64] ============
    if (b < 3) {
        int c = b * 256 + t;
        float s = 0.f, s2 = 0.f;
        for (int r = 0; r < NG; ++r) {
            float v;
            if (c < 512) v = Zp[r * D2 + c];
            else if (c < 640) {
                int o = c - 512;
                float sm = 0.f;
                #pragma unroll
                for (int q = 0; q < 4; ++q) sm += Zp3[(size_t)(r * 4 + q) * 256 + o];
                v = sm * (1.f / NPG);
            } else {
                int o = c - 640;
                float mx = -BIG;
                #pragma unroll
                for (int q = 0; q < 4; ++q) mx = fmaxf(mx, Zp3[(size_t)(r * 4 + q) * 256 + 128 + o]);
                v = mx;
            }
            s += v; s2 = fmaf(v, v, s2);
        }
        float m   = s * (1.f / NG);
        float var = s2 * (1.f / NG) - m * m;
        float sc  = rsqrtf(var + BNEPS) * bng[c];
        float bt  = bnb[c];
        for (int r = 0; r < NG; ++r) {
            float v;
            if (c < 512) v = Zp[r * D2 + c];
            else if (c < 640) {
                int o = c - 512;
                float sm = 0.f;
                #pragma unroll
                for (int q = 0; q < 4; ++q) sm += Zp3[(size_t)(r * 4 + q) * 256 + o];
                v = sm * (1.f / NPG);
            } else {
                int o = c - 640;
                float mx = -BIG;
                #pragma unroll
                for (int q = 0; q < 4; ++q) mx = fmaxf(mx, Zp3[(size_t)(r * 4 + q) * 256 + 128 + o]);
                v = mx;
            }
            ZT0[c * NG + r] = (v - m) * sc + bt;
        }
    }
    grid.sync();   // S5

    // ============ Phases 5-9: MLP layers (4 cols/block, W panel in LDS, 4-way K split) ============
    for (int l = 0; l < 5; ++l) {
        const float* zin  = (l & 1) ? ZT1 : ZT0;
        float*       zout = (l & 1) ? ZT0 : ZT1;
        const float* W = linW + (size_t)l * D2 * D2;
        if (b < 192) {
            const int c0 = b * 4;
            for (int u = t; u < D2; u += 256)
                *(float4*)&Ps[u * 4] = *(const float4*)&W[(size_t)u * D2 + c0];
            __syncthreads();
            int row = t & 63, kq = t >> 6;
            const float* zp = zin + kq * 192 * NG + row;
            const float* wp = &Ps[kq * 192 * 4];
            float s0 = 0.f, s1 = 0.f, s2 = 0.f, s3 = 0.f;
            #pragma unroll 8
            for (int k = 0; k < 192; ++k) {
                float z  = zp[k * NG];
                float4 w = *(const float4*)&wp[k * 4];
                s0 = fmaf(z, w.x, s0); s1 = fmaf(z, w.y, s1);
                s2 = fmaf(z, w.z, s2); s3 = fmaf(z, w.w, s3);
            }
            red[(0 * 4 + kq) * 64 + row] = s0;
            red[(1 * 4 + kq) * 64 + row] = s1;
            red[(2 * 4 + kq) * 64 + row] = s2;
            red[(3 * 4 + kq) * 64 + row] = s3;
            __syncthreads();
            int c = t >> 6, r2 = t & 63;
            float v = red[(c * 4 + 0) * 64 + r2] + red[(c * 4 + 1) * 64 + r2]
                    + red[(c * 4 + 2) * 64 + r2] + red[(c * 4 + 3) * 64 + r2];
            v = leaky(v + linb[l * D2 + c0 + c]);
            zout[(c0 + c) * NG + r2] = v;
            __syncthreads();   // Ps reuse next layer
        }
        grid.sync();   // S6..S10
    }

    // ============ Phase 10: output head ============
    if (b == 0) {
        const float* zin = ZT1;   // after 5 layers, result is in ZT1
        for (int u = t; u < D2; u += 256) Ps[u] = outW[u];
        __syncthreads();
        int row = t & 63, kq = t >> 6;
        const float* zp = zin + kq * 192 * NG + row;
        float s = 0.f;
        #pragma unroll 8
        for (int k = 0; k < 192; ++k) s = fmaf(zp[k * NG], Ps[kq * 192 + k], s);
        red[kq * 64 + row] = s;
        __syncthreads();
        if (t < 64)
            out[t] = red[t] + red[64 + t] + red[128 + t] + red[192 + t] + outb[0];
    }
}

extern "C" void kernel_launch(void* const* d_in, const int* in_sizes, int n_in,
                              void* d_out, int out_size, void* d_ws, size_t ws_size,
                              hipStream_t stream)
{
    (void)in_sizes; (void)n_in; (void)out_size; (void)ws_size;
    const float* x       = (const float*)d_in[0];
    // d_in[1] = batch: fixed structure (i/128), unused
    const float* conv1_W = (const float*)d_in[2];
    const float* conv1_b = (const float*)d_in[3];
    const float* convs_W = (const float*)d_in[4];
    const float* convs_b = (const float*)d_in[5];
    const float* bn_g    = (const float*)d_in[6];
    const float* bn_b    = (const float*)d_in[7];
    const float* lin_W   = (const float*)d_in[8];
    const float* lin_b   = (const float*)d_in[9];
    const float* out_W   = (const float*)d_in[10];
    const float* out_b   = (const float*)d_in[11];

    float* A   = (float*)d_ws;           // 1M floats
    float* H1  = A   + (1 << 20);        // 1M
    float* H2  = H1  + (1 << 20);        // 1M
    float* Zp  = H2  + (1 << 20);        // 49152
    float* Zp3 = Zp  + NG * D2;          // 65536
    float* ZT0 = Zp3 + NG * 4 * 256;     // 49152
    float* ZT1 = ZT0 + NG * D2;          // 49152
    float* outp = (float*)d_out;

    void* args[] = {
        (void*)&x, (void*)&conv1_W, (void*)&conv1_b, (void*)&convs_W, (void*)&convs_b,
        (void*)&bn_g, (void*)&bn_b, (void*)&lin_W, (void*)&lin_b,
        (void*)&out_W, (void*)&out_b,
        (void*)&A, (void*)&H1, (void*)&H2, (void*)&Zp, (void*)&Zp3,
        (void*)&ZT0, (void*)&ZT1, (void*)&outp
    };
    hipLaunchCooperativeKernel((void*)k_mega, dim3(256), dim3(256), args, 0, stream);
}